// Round 1
// baseline (451.101 us; speedup 1.0000x reference)
//
#include <hip/hip_runtime.h>
#include <hip/hip_bf16.h>

// Problem: H=32 heads, M=512 queries, D=128, P=4096 KV rows, fp32 in/out.
// Output = multi-head attention only (reference's RMSNorm/QKV is dead code).

#define NH   32
#define MQ   512
#define DD   128
#define PKV  4096
#define QBLK 64
#define KVB  64
#define NIT  (PKV / KVB)   // 64 iterations
#define VSTR 68            // Vt row stride (elements): 8B-aligned b64 reads, conflict-free

typedef float  f32x4  __attribute__((ext_vector_type(4)));
typedef __bf16 bf16x4 __attribute__((ext_vector_type(4)));
typedef __bf16 bf16x8 __attribute__((ext_vector_type(8)));

__global__ __launch_bounds__(256, 1)
void attn_fused_kernel(const float* __restrict__ qg,
                       const float* __restrict__ kg,
                       const float* __restrict__ vg,
                       float* __restrict__ outg)
{
    // K tile: row-major [64][128] bf16, XOR-swizzled (byte ^= (row&7)<<4)
    __shared__ __align__(16) __bf16 k_lds[KVB * DD];
    // V tile: transposed [128][68] bf16 (d-major), stride 68
    __shared__ __align__(16) __bf16 vt_lds[DD * VSTR];

    const int tid  = threadIdx.x;
    const int lane = tid & 63;
    const int w    = tid >> 6;      // wave 0..3, owns q-rows [16w,16w+16)
    const int q16  = lane & 15;
    const int hi   = lane >> 4;

    const int bx = blockIdx.x;
    const int h  = bx & 31;         // head  (bx%8 = h%8 -> all 8 tiles of a head share an XCD)
    const int qt = bx >> 5;         // q tile 0..7

    // ---- Q fragments: Q[rowq][32*ks + 8*hi + v], pre-scaled by scale*log2(e) ----
    const float SCL = 0.08838834764831845f * 1.4426950408889634f;
    const int rowq = qt * QBLK + w * 16 + q16;
    const float* qrow = qg + ((size_t)h * MQ + rowq) * DD;
    bf16x8 qf[4];
#pragma unroll
    for (int ks = 0; ks < 4; ++ks) {
        const float* p = qrow + ks * 32 + hi * 8;
        f32x4 a = *(const f32x4*)(p);
        f32x4 b = *(const f32x4*)(p + 4);
#pragma unroll
        for (int c = 0; c < 4; ++c) {
            qf[ks][c]     = (__bf16)(a[c] * SCL);
            qf[ks][c + 4] = (__bf16)(b[c] * SCL);
        }
    }

    // ---- staging assignment: thread covers (kv = 8j + tid/32, d = 4*(tid%32)) ----
    const int srow = tid >> 5;        // 0..7
    const int scol = (tid & 31) * 4;  // 0..124
    const float* kbase = kg + (size_t)h * PKV * DD;
    const float* vbase = vg + (size_t)h * PKV * DD;

    f32x4 kreg[8], vreg[8];
#pragma unroll
    for (int j = 0; j < 8; ++j) {
        size_t off = (size_t)(8 * j + srow) * DD + scol;
        kreg[j] = *(const f32x4*)(kbase + off);
        vreg[j] = *(const f32x4*)(vbase + off);
    }

    // ---- accumulator state ----
    f32x4 o[8];
#pragma unroll
    for (int dt = 0; dt < 8; ++dt) o[dt] = (f32x4){0.f, 0.f, 0.f, 0.f};
    float m_run = -1e30f;
    float l_run = 0.f;

    for (int it = 0; it < NIT; ++it) {
        __syncthreads();   // previous tile's compute done -> LDS writable
#pragma unroll
        for (int j = 0; j < 8; ++j) {
            int kv = 8 * j + srow;
            bf16x4 pk;
#pragma unroll
            for (int c = 0; c < 4; ++c) pk[c] = (__bf16)kreg[j][c];
            int idx = kv * DD + (scol ^ ((kv & 7) << 3));   // swizzled, stays b64-aligned
            *(bf16x4*)&k_lds[idx] = pk;
#pragma unroll
            for (int c = 0; c < 4; ++c)
                vt_lds[(scol + c) * VSTR + kv] = (__bf16)vreg[j][c];
        }
        __syncthreads();   // LDS ready

        // prefetch next tile (global latency hides under MFMA/softmax below)
        if (it + 1 < NIT) {
            const float* kb = kbase + (size_t)(it + 1) * KVB * DD;
            const float* vb = vbase + (size_t)(it + 1) * KVB * DD;
#pragma unroll
            for (int j = 0; j < 8; ++j) {
                size_t off = (size_t)(8 * j + srow) * DD + scol;
                kreg[j] = *(const f32x4*)(kb + off);
                vreg[j] = *(const f32x4*)(vb + off);
            }
        }

        // ---- S^T = K · Q^T : tile t covers kv [16t,16t+16); lane reg r = kv 16t+4hi+r, q=q16
        f32x4 st[4];
#pragma unroll
        for (int t = 0; t < 4; ++t) st[t] = (f32x4){0.f, 0.f, 0.f, 0.f};
#pragma unroll
        for (int ks = 0; ks < 4; ++ks) {
#pragma unroll
            for (int t = 0; t < 4; ++t) {
                int kvrow = t * 16 + q16;
                int d0 = ks * 32 + hi * 8;
                bf16x8 kf = *(const bf16x8*)&k_lds[kvrow * DD + (d0 ^ ((kvrow & 7) << 3))];
                st[t] = __builtin_amdgcn_mfma_f32_16x16x32_bf16(kf, qf[ks], st[t], 0, 0, 0);
            }
        }

        // ---- online softmax (scores already in log2 units) ----
        float mt = st[0][0];
#pragma unroll
        for (int t = 0; t < 4; ++t)
#pragma unroll
            for (int r = 0; r < 4; ++r) mt = fmaxf(mt, st[t][r]);
        mt = fmaxf(mt, __shfl_xor(mt, 16));
        mt = fmaxf(mt, __shfl_xor(mt, 32));
        float m_new = fmaxf(m_run, mt);
        float alpha = __builtin_amdgcn_exp2f(m_run - m_new);

        float lsum = 0.f;
        bf16x8 pa[2];   // PV A-frags: pa[c][v] = P[q16][32c + 16(v>>2) + 4hi + (v&3)]
#pragma unroll
        for (int t = 0; t < 4; ++t) {
#pragma unroll
            for (int r = 0; r < 4; ++r) {
                float pv = __builtin_amdgcn_exp2f(st[t][r] - m_new);
                lsum += pv;
                pa[t >> 1][(t & 1) * 4 + r] = (__bf16)pv;
            }
        }
        lsum += __shfl_xor(lsum, 16);
        lsum += __shfl_xor(lsum, 32);
        l_run = l_run * alpha + lsum;
        m_run = m_new;

        // rescale O (O rows are q = 4*hi + r; alpha lives at lane q)
        f32x4 av;
#pragma unroll
        for (int r = 0; r < 4; ++r) av[r] = __shfl(alpha, hi * 4 + r);
#pragma unroll
        for (int dt = 0; dt < 8; ++dt)
#pragma unroll
            for (int r = 0; r < 4; ++r) o[dt][r] *= av[r];

        // ---- O += P · V : B slot v = V[32c + 16(v>>2) + 4hi + (v&3)][16dt + q16] ----
#pragma unroll
        for (int c = 0; c < 2; ++c) {
#pragma unroll
            for (int dt = 0; dt < 8; ++dt) {
                int idx = (dt * 16 + q16) * VSTR + c * 32 + hi * 4;
                bf16x4 v0 = *(const bf16x4*)&vt_lds[idx];
                bf16x4 v1 = *(const bf16x4*)&vt_lds[idx + 16];
                bf16x8 vf;
#pragma unroll
                for (int e = 0; e < 4; ++e) { vf[e] = v0[e]; vf[e + 4] = v1[e]; }
                o[dt] = __builtin_amdgcn_mfma_f32_16x16x32_bf16(pa[c], vf, o[dt], 0, 0, 0);
            }
        }
    }

    // ---- epilogue: divide by l, write out[m][h*128 + d] ----
    f32x4 linv;
#pragma unroll
    for (int r = 0; r < 4; ++r) linv[r] = 1.0f / __shfl(l_run, hi * 4 + r);
    const int row0 = qt * QBLK + w * 16;
#pragma unroll
    for (int dt = 0; dt < 8; ++dt) {
#pragma unroll
        for (int r = 0; r < 4; ++r) {
            int row = row0 + hi * 4 + r;
            int col = h * DD + dt * 16 + q16;
            outg[(size_t)row * (NH * DD) + col] = o[dt][r] * linv[r];
        }
    }
}

extern "C" void kernel_launch(void* const* d_in, const int* in_sizes, int n_in,
                              void* d_out, int out_size, void* d_ws, size_t ws_size,
                              hipStream_t stream) {
    (void)in_sizes; (void)n_in; (void)d_ws; (void)ws_size; (void)out_size;
    // inputs: 0=X (unused), 1=weight (unused), 2=W (unused), 3=q, 4=cache_K, 5=cache_V
    const float* q  = (const float*)d_in[3];
    const float* ck = (const float*)d_in[4];
    const float* cv = (const float*)d_in[5];
    float* out = (float*)d_out;
    attn_fused_kernel<<<dim3(NH * (MQ / QBLK)), dim3(256), 0, stream>>>(q, ck, cv, out);
}